// Round 9
// baseline (179.146 us; speedup 1.0000x reference)
//
#include <hip/hip_runtime.h>
#include <math.h>

#define D_MODEL 4096
#define N_EXP   64
#define SLABF   260   // slab stride in floats (1040B) -> spreads ds_read banks

typedef _Float16 half8 __attribute__((ext_vector_type(8)));
typedef float    f32x4 __attribute__((ext_vector_type(4)));

// ---------------------------------------------------------------------------
// Prep: W[64][4096] fp32 -> fragment-ordered fp16 hi/lo arrays (in d_ws).
// Ws = W*64; hi = fp16(Ws); lo = fp16((Ws-hi)*4096). Fragment order:
// element (kstep,nt,lane,j) at ((kstep*4+nt)*64+lane)*8+j, expert
// e = nt*16+(lane&15), k = kstep*32+(lane>>4)*8+j. (Verified R4-R8.)
// ---------------------------------------------------------------------------
__global__ __launch_bounds__(256)
void wprep_kernel(const float* __restrict__ W,
                  _Float16* __restrict__ whf, _Float16* __restrict__ wlf) {
    const int gid   = blockIdx.x * 256 + threadIdx.x;   // 0..32767
    const int lane  = gid & 63;
    const int ntk   = gid >> 6;
    const int nt    = ntk & 3;
    const int kstep = ntk >> 2;
    const int e  = nt * 16 + (lane & 15);
    const int k0 = kstep * 32 + (lane >> 4) * 8;

    const float* src = W + (size_t)e * D_MODEL + k0;
    float4 w0 = *(const float4*)(src);
    float4 w1 = *(const float4*)(src + 4);
    float wv[8] = {w0.x, w0.y, w0.z, w0.w, w1.x, w1.y, w1.z, w1.w};

    half8 hh, ll;
    #pragma unroll
    for (int j = 0; j < 8; ++j) {
        float ws = wv[j] * 64.0f;
        _Float16 h = (_Float16)ws;
        hh[j] = h;
        ll[j] = (_Float16)((ws - (float)h) * 4096.0f);
    }
    *(half8*)(whf + (size_t)gid * 8) = hh;
    *(half8*)(wlf + (size_t)gid * 8) = ll;
}

// global -> LDS direct (16B/lane, dest = wave-uniform base + lane*16)
#define GLD16(gp, lp) __builtin_amdgcn_global_load_lds( \
    (const __attribute__((address_space(1))) unsigned int*)(const void*)(gp), \
    (__attribute__((address_space(3))) unsigned int*)(void*)(lp), 16, 0, 0)

__device__ __forceinline__ void cvt_hilo(const float4 a, const float4 b,
                                         half8& hi, half8& lo) {
    float av[8] = {a.x, a.y, a.z, a.w, b.x, b.y, b.z, b.w};
    #pragma unroll
    for (int j = 0; j < 8; ++j) {
        _Float16 h = (_Float16)av[j];
        hi[j] = h;
        lo[j] = (_Float16)((av[j] - (float)h) * 4096.0f);
    }
}

// ---------------------------------------------------------------------------
// Main: 512 thr = 8 waves x 16 tokens = 128 tokens/block, 256 blocks (1/CU).
// 64 groups of 2 ksteps. TRIPLE-buffered A+B LDS (146KB); group g reads
// buf g%3 and stages group g+2 into buf (g+2)%3. Barriers are counted
// `s_waitcnt vmcnt(6)` + raw s_barrier: the just-issued 6 stage loads stay
// in flight across the barrier -> no fresh-load drain, HBM never idles.
//  - A: wave w stages its 16 rows as 4 slab loads (row 4s+(l>>4), 16B chunk
//    l&15 -> contiguous 256B/row, fully coalesced).
//  - B: wave w stages (ksl=w&1, hi/lo=(w>>1)&1, nt=(w>>2)*2 .. +1).
// ---------------------------------------------------------------------------
__global__ __launch_bounds__(512, 1)
void router_kernel(const float* __restrict__ x,
                   const _Float16* __restrict__ whf,
                   const _Float16* __restrict__ wlf,
                   float* __restrict__ out, int ntok) {
    __shared__ __align__(16) float    sA[3 * 8 * 4 * SLABF];   // 99840 B
    __shared__ __align__(16) _Float16 sB[3][2][2][4][512];     // 49152 B

    const int tid  = threadIdx.x;
    const int w    = tid >> 6;    // wave 0..7
    const int l    = tid & 63;
    const int tok0 = blockIdx.x * 128;

    // A stage sources: slab s -> row w*16 + s*4 + (l>>4), float chunk (l&15)*4
    const float* a_s0 = x + (size_t)(tok0 + w * 16 + 0 + (l >> 4)) * D_MODEL + (l & 15) * 4;
    const float* a_s1 = a_s0 + (size_t)4 * D_MODEL;
    const float* a_s2 = a_s0 + (size_t)8 * D_MODEL;
    const float* a_s3 = a_s0 + (size_t)12 * D_MODEL;
    // B stage role of this wave
    const int bksl = w & 1;
    const int bhl  = (w >> 1) & 1;
    const int bnt  = (w >> 2) * 2;
    const _Float16* bsrc = (bhl ? wlf : whf) + (size_t)l * 8;

    f32x4 hh[4], cc[4];
    #pragma unroll
    for (int nt = 0; nt < 4; ++nt) { hh[nt] = (f32x4)0.0f; cc[nt] = (f32x4)0.0f; }

#define STAGE(T, SBUF)                                                         \
    {                                                                          \
        const int kf = (T) * 64;                                               \
        GLD16(a_s0 + kf, &sA[(((SBUF) * 8 + w) * 4 + 0) * SLABF]);             \
        GLD16(a_s1 + kf, &sA[(((SBUF) * 8 + w) * 4 + 1) * SLABF]);             \
        GLD16(a_s2 + kf, &sA[(((SBUF) * 8 + w) * 4 + 2) * SLABF]);             \
        GLD16(a_s3 + kf, &sA[(((SBUF) * 8 + w) * 4 + 3) * SLABF]);             \
        const size_t bo = (size_t)(((T) * 2 + bksl) * 4 + bnt) * 512;          \
        GLD16(bsrc + bo,       &sB[SBUF][bksl][bhl][bnt][0]);                  \
        GLD16(bsrc + bo + 512, &sB[SBUF][bksl][bhl][bnt + 1][0]);              \
    }

#define STEP(KSL, RB)                                                          \
    {                                                                          \
        const float* ap = &sA[(((RB) * 8 + w) * 4 + ((l & 15) >> 2)) * SLABF   \
                              + ((l & 15) & 3) * 64 + (KSL) * 32 + (l >> 4) * 8]; \
        float4 a0 = *(const float4*)ap;                                        \
        float4 a1 = *(const float4*)(ap + 4);                                  \
        half8 ah, al_;                                                         \
        cvt_hilo(a0, a1, ah, al_);                                             \
        half8 bh[4], bl[4];                                                    \
        _Pragma("unroll")                                                      \
        for (int nt = 0; nt < 4; ++nt) {                                       \
            bh[nt] = *(const half8*)&sB[RB][KSL][0][nt][l * 8];                \
            bl[nt] = *(const half8*)&sB[RB][KSL][1][nt][l * 8];                \
        }                                                                      \
        _Pragma("unroll")                                                      \
        for (int nt = 0; nt < 4; ++nt)                                         \
            hh[nt] = __builtin_amdgcn_mfma_f32_16x16x32_f16(ah, bh[nt], hh[nt], 0, 0, 0); \
        _Pragma("unroll")                                                      \
        for (int nt = 0; nt < 4; ++nt)                                         \
            cc[nt] = __builtin_amdgcn_mfma_f32_16x16x32_f16(ah, bl[nt], cc[nt], 0, 0, 0); \
        _Pragma("unroll")                                                      \
        for (int nt = 0; nt < 4; ++nt)                                         \
            cc[nt] = __builtin_amdgcn_mfma_f32_16x16x32_f16(al_, bh[nt], cc[nt], 0, 0, 0); \
    }

    // counted-vmcnt barrier: this group's 6 stage loads stay in flight
#define SYNC6 { asm volatile("s_waitcnt vmcnt(6) lgkmcnt(0)" ::: "memory");    \
                __builtin_amdgcn_sched_barrier(0);                             \
                __builtin_amdgcn_s_barrier();                                  \
                __builtin_amdgcn_sched_barrier(0); }
#define SYNC0 { asm volatile("s_waitcnt vmcnt(0) lgkmcnt(0)" ::: "memory");    \
                __builtin_amdgcn_sched_barrier(0);                             \
                __builtin_amdgcn_s_barrier();                                  \
                __builtin_amdgcn_sched_barrier(0); }

    // prologue: stage groups 0,1; wait for group 0 (group 1 stays in flight)
    STAGE(0, 0)
    STAGE(1, 1)
    SYNC6

    // groups 0..59 (buffers rotate 0,1,2; stage target = (g+2)%3, uniform)
    for (int i = 0; i < 20; ++i) {
        const int g = i * 3;
        STAGE(g + 2, 2) STEP(0, 0) STEP(1, 0) SYNC6
        STAGE(g + 3, 0) STEP(0, 1) STEP(1, 1) SYNC6
        STAGE(g + 4, 1) STEP(0, 2) STEP(1, 2) SYNC6
    }
    // groups 60..63 tail
    STAGE(62, 2) STEP(0, 0) STEP(1, 0) SYNC6
    STAGE(63, 0) STEP(0, 1) STEP(1, 1) SYNC6
    STEP(0, 2) STEP(1, 2) SYNC0
    STEP(0, 0) STEP(1, 0)

#undef STAGE
#undef STEP
#undef SYNC6
#undef SYNC0

    // logits = (hh + cc*2^-12) * 2^-6; top-2 over 16-lane butterfly
    float tt[4][4];   // [nt][q]
    #pragma unroll
    for (int nt = 0; nt < 4; ++nt) {
        f32x4 tot = (hh[nt] + cc[nt] * (1.0f / 4096.0f)) * (1.0f / 64.0f);
        tt[nt][0] = tot.x; tt[nt][1] = tot.y; tt[nt][2] = tot.z; tt[nt][3] = tot.w;
    }

    float* out_e = out + (size_t)2 * ntok;

    #pragma unroll
    for (int q = 0; q < 4; ++q) {
        // C/D layout: col = lane&15 (expert sub), row = (lane>>4)*4 + q (token)
        float v1 = -3.0e38f, v2 = -3.0e38f;
        int   i1 = 1 << 30,  i2 = 1 << 30;
        #pragma unroll
        for (int nt = 0; nt < 4; ++nt) {
            float v  = tt[nt][q];
            int   id = nt * 16 + (l & 15);
            if (v > v1 || (v == v1 && id < i1)) {
                v2 = v1; i2 = i1; v1 = v; i1 = id;
            } else if (v > v2 || (v == v2 && id < i2)) {
                v2 = v; i2 = id;
            }
        }
        #pragma unroll
        for (int m = 1; m < 16; m <<= 1) {
            float ov1 = __shfl_xor(v1, m, 64);
            int   oi1 = __shfl_xor(i1, m, 64);
            float ov2 = __shfl_xor(v2, m, 64);
            int   oi2 = __shfl_xor(i2, m, 64);
            bool ofirst = (ov1 > v1) || (ov1 == v1 && oi1 < i1);
            if (ofirst) {
                bool s2 = (ov2 > v1) || (ov2 == v1 && oi2 < i1);
                v2 = s2 ? ov2 : v1;  i2 = s2 ? oi2 : i1;
                v1 = ov1;            i1 = oi1;
            } else {
                bool s2 = (ov1 > v2) || (ov1 == v2 && oi1 < i2);
                v2 = s2 ? ov1 : v2;  i2 = s2 ? oi1 : i2;
            }
        }

        if ((l & 15) == 0) {
            const int tok = tok0 + w * 16 + (l >> 4) * 4 + q;
            float e = expf(v2 - v1);     // <= 1
            float d = 1.0f + e;
            out[2 * tok + 0] = 1.0f / d;
            out[2 * tok + 1] = e / d;
            out_e[2 * tok + 0] = (float)i1;
            out_e[2 * tok + 1] = (float)i2;
        }
    }
}

extern "C" void kernel_launch(void* const* d_in, const int* in_sizes, int n_in,
                              void* d_out, int out_size, void* d_ws, size_t ws_size,
                              hipStream_t stream) {
    const float* x = (const float*)d_in[0];
    const float* W = (const float*)d_in[1];
    float* out = (float*)d_out;
    const int ntok = in_sizes[0] / D_MODEL;   // 32768

    _Float16* whf = (_Float16*)d_ws;                           // 512 KB
    _Float16* wlf = (_Float16*)d_ws + (size_t)N_EXP * D_MODEL; // 512 KB

    wprep_kernel<<<dim3(128), dim3(256), 0, stream>>>(W, whf, wlf);
    router_kernel<<<dim3(ntok / 128), dim3(512), 0, stream>>>(x, whf, wlf, out, ntok);
}